// Round 1
// baseline (309.482 us; speedup 1.0000x reference)
//
#include <hip/hip_runtime.h>

// Round 6: 2 px/thread along w. Widen the dominant 210 MB kernel stream from
// 4B/lane scalar loads to 8B/lane f32x2 nontemporal loads; out stores from
// float2 to float4 (16B/lane); burst patch from 90 scalar to 45 f32x2 loads.
// Same total bytes (~241 MB, ~38 us floor @ 6.3 TB/s); fewer VMEM issue slots.
//
// burst:   (nd=32, c=3, 128, 128) fp32
// kernels: (nd=32, r=4, 5, 5, 128, 128) fp32
// out:     (nd=32, c=3, 256, 256) fp32 (pixel-shuffle s=2)
#define HH 128
#define WW 128
#define CC 3
#define RR 4
#define KK 5
#define ND 32
#define HW (HH*WW)

typedef float f32x2 __attribute__((ext_vector_type(2)));
typedef float f32x4 __attribute__((ext_vector_type(4)));

__global__ __launch_bounds__(256) void adaptive_conv_ps(
    const float* __restrict__ burst,
    const float* __restrict__ kern,
    float* __restrict__ out)
{
    int t  = blockIdx.x * blockDim.x + threadIdx.x;
    int wp = t & (WW / 2 - 1);        // pair index 0..63
    int h  = (t >> 6) & (HH - 1);
    int nd = t >> 13;
    int w0 = wp * 2;                  // left pixel of the pair

    const float* bptr = burst + (size_t)nd * CC * HW;
    const float* kptr = kern  + (size_t)nd * RR * KK * KK * HW + h * WW + w0;

    const bool left  = (wp >= 1);     // pair (w0-2, w0-1) fully in-bounds
    const bool right = (wp <= 62);    // pair (w0+2, w0+3) fully in-bounds
    const f32x2 zz = {0.0f, 0.0f};

    // 3 x 5 x 6 burst patch (cols x = w0-2 .. w0+3), zero-padded borders.
    // Aligned f32x2 pairs: each pair is fully valid or fully OOB in x.
    float patch[CC][KK][6];
#pragma unroll
    for (int c = 0; c < CC; ++c) {
#pragma unroll
        for (int i = 0; i < KK; ++i) {
            int  y  = h + i - 2;
            bool yv = (unsigned)y < (unsigned)HH;
            const float* row = bptr + c * HW + y * WW + w0;
            f32x2 p0 = (yv && left)  ? *(const f32x2*)(row - 2) : zz;
            f32x2 p1 = (yv)          ? *(const f32x2*)(row)     : zz;
            f32x2 p2 = (yv && right) ? *(const f32x2*)(row + 2) : zz;
            patch[c][i][0] = p0.x; patch[c][i][1] = p0.y;
            patch[c][i][2] = p1.x; patch[c][i][3] = p1.y;
            patch[c][i][4] = p2.x; patch[c][i][5] = p2.y;
        }
    }

    // acc[c][r]: .x = left pixel, .y = right pixel
    f32x2 acc[CC][RR];
#pragma unroll
    for (int c = 0; c < CC; ++c)
#pragma unroll
        for (int r = 0; r < RR; ++r)
            acc[c][r] = zz;

    // Stream 100 per-pixel kernel taps as f32x2 (lanes stride 2 floats ->
    // 8B/lane fully coalesced). Read-once -> nontemporal.
#pragma unroll
    for (int r = 0; r < RR; ++r) {
#pragma unroll
        for (int i = 0; i < KK; ++i) {
#pragma unroll
            for (int j = 0; j < KK; ++j) {
                f32x2 kv = __builtin_nontemporal_load(
                    (const f32x2*)(kptr + (size_t)((r * KK + i) * KK + j) * HW));
#pragma unroll
                for (int c = 0; c < CC; ++c) {
                    acc[c][r].x += kv.x * patch[c][i][j];
                    acc[c][r].y += kv.y * patch[c][i][j + 1];
                }
            }
        }
    }

    // Pixel-shuffle store: out[nd, c, 2h+si, 4wp .. 4wp+3] as one float4.
    // cols: 2*w0+sj (px0), 2*w0+2+sj (px1)
#pragma unroll
    for (int c = 0; c < CC; ++c) {
#pragma unroll
        for (int si = 0; si < 2; ++si) {
            f32x4 v = { acc[c][si * 2 + 0].x, acc[c][si * 2 + 1].x,
                        acc[c][si * 2 + 0].y, acc[c][si * 2 + 1].y };
            float* o = out + (((size_t)(nd * CC + c) * (2 * HH) + (2 * h + si)) * (2 * WW)) + 2 * w0;
            *(f32x4*)o = v;
        }
    }
}

extern "C" void kernel_launch(void* const* d_in, const int* in_sizes, int n_in,
                              void* d_out, int out_size, void* d_ws, size_t ws_size,
                              hipStream_t stream) {
    const float* burst = (const float*)d_in[0];
    const float* kern  = (const float*)d_in[1];
    float* out = (float*)d_out;

    const int total = ND * HH * WW / 2;      // 262144 threads, 2 px/thread
    adaptive_conv_ps<<<total / 256, 256, 0, stream>>>(burst, kern, out);
}

// Round 2
// 281.256 us; speedup vs baseline: 1.1004x; 1.1004x over previous
//
#include <hip/hip_runtime.h>

// Round 7: REVERT to verified 1 px/thread structure (294.5 us; the 2 px/thread
// widening regressed to 309.5 us -- traded TLP for VMEM-issue savings the
// memory system didn't need). Only delta vs the verified best: nontemporal
// STORES on the write-once 25 MB output (keep burst lines L2-resident).
//
// burst:   (nd=32, c=3, 128, 128) fp32   -- L2-hot, reused 25x
// kernels: (nd=32, r=4, 5, 5, 128, 128) fp32 -- 210 MB read-once stream (NT loads)
// out:     (nd=32, c=3, 256, 256) fp32   -- 25 MB write-once (NT stores)
#define HH 128
#define WW 128
#define CC 3
#define RR 4
#define KK 5
#define ND 32
#define HW (HH*WW)

typedef float f32x2 __attribute__((ext_vector_type(2)));

__global__ __launch_bounds__(256) void adaptive_conv_ps(
    const float* __restrict__ burst,
    const float* __restrict__ kern,
    float* __restrict__ out)
{
    int t  = blockIdx.x * blockDim.x + threadIdx.x;
    int w  = t & (WW - 1);
    int h  = (t >> 7) & (HH - 1);
    int nd = t >> 14;

    const float* bptr = burst + (size_t)nd * CC * HW;
    const float* kptr = kern  + (size_t)nd * RR * KK * KK * HW + h * WW + w;

    // 3x5x5 burst patch (zero-padded borders); burst slice is L2-hot (196 KB/nd).
    float patch[CC][KK * KK];
#pragma unroll
    for (int c = 0; c < CC; ++c) {
#pragma unroll
        for (int i = 0; i < KK; ++i) {
            int  y  = h + i - 2;
            bool yv = (unsigned)y < (unsigned)HH;
#pragma unroll
            for (int j = 0; j < KK; ++j) {
                int  x = w + j - 2;
                bool v = yv && ((unsigned)x < (unsigned)WW);
                patch[c][i * KK + j] = v ? bptr[c * HW + y * WW + x] : 0.0f;
            }
        }
    }

    float acc[CC][RR];
#pragma unroll
    for (int c = 0; c < CC; ++c)
#pragma unroll
        for (int r = 0; r < RR; ++r)
            acc[c][r] = 0.0f;

    // Stream 100 per-pixel kernel taps, coalesced along w; read-once ->
    // nontemporal (don't allocate in L1/L2, keep burst/out lines resident).
#pragma unroll
    for (int r = 0; r < RR; ++r) {
#pragma unroll
        for (int ij = 0; ij < KK * KK; ++ij) {
            float kv = __builtin_nontemporal_load(
                kptr + (size_t)(r * KK * KK + ij) * HW);
#pragma unroll
            for (int c = 0; c < CC; ++c)
                acc[c][r] += kv * patch[c][ij];
        }
    }

    // Pixel-shuffle store: out[nd, c, 2h+si, 2w+sj] = acc[c][si*2+sj]
    // Write-once, never re-read -> nontemporal float2 stores.
#pragma unroll
    for (int c = 0; c < CC; ++c) {
#pragma unroll
        for (int si = 0; si < 2; ++si) {
            f32x2 v = { acc[c][si * 2 + 0], acc[c][si * 2 + 1] };
            float* o = out + (((size_t)(nd * CC + c) * (2 * HH) + (2 * h + si)) * (2 * WW)) + 2 * w;
            __builtin_nontemporal_store(v, (f32x2*)o);
        }
    }
}

extern "C" void kernel_launch(void* const* d_in, const int* in_sizes, int n_in,
                              void* d_out, int out_size, void* d_ws, size_t ws_size,
                              hipStream_t stream) {
    const float* burst = (const float*)d_in[0];
    const float* kern  = (const float*)d_in[1];
    float* out = (float*)d_out;

    const int total = ND * HH * WW;          // 524288 threads, 1 px/thread
    adaptive_conv_ps<<<total / 256, 256, 0, stream>>>(burst, kern, out);
}